// Round 14
// baseline (220.757 us; speedup 1.0000x reference)
//
#include <hip/hip_runtime.h>

#define BATCH 16
#define CIN   1024
#define HID   256
#define HW    4096

typedef __attribute__((ext_vector_type(8))) short bf16x8;
typedef __attribute__((ext_vector_type(4))) float f32x4;

struct __align__(16) f4  { float v[4]; };
struct __align__(8)  us4 { unsigned short v[4]; };
struct __align__(16) us8 { unsigned short v[8]; };

__device__ __forceinline__ float bf2f(unsigned short u) {
  unsigned int x = ((unsigned int)u) << 16;
  return __builtin_bit_cast(float, x);
}
__device__ __forceinline__ unsigned short f2bf(float f) {
  unsigned int u = __builtin_bit_cast(unsigned int, f);
  u += 0x7fff + ((u >> 16) & 1);            // round-to-nearest-even
  return (unsigned short)(u >> 16);
}

// lgkm-only barrier: drain ds ops, leave ALL vmem prefetch in flight
#define LGWB() do { __builtin_amdgcn_sched_barrier(0); \
  asm volatile("s_waitcnt lgkmcnt(0)" ::: "memory"); \
  __builtin_amdgcn_s_barrier(); \
  __builtin_amdgcn_sched_barrier(0); } while (0)

// Pre-convert fp32 [256][KD] weights into per-lane bf16 MFMA A-fragments:
// unit u -> [tile][wm][kk][mi][lane], 16 B each. Trailing blocks zero ctx/bn sums.
__global__ __launch_bounds__(256)
void prep_kernel(const float* __restrict__ A1, unsigned short* __restrict__ O1,
                 const float* __restrict__ A2, unsigned short* __restrict__ O2,
                 float* __restrict__ zbuf)
{
  const int bidx = blockIdx.x;
  if (bidx >= 160) {                        // zero ctx_sum[16384] + bn_sums[512]
    int idx = (bidx - 160) * 256 + threadIdx.x;
    if (idx < 16896) zbuf[idx] = 0.f;
    return;
  }
  const float* A; unsigned short* O; int KD, u;
  if (bidx < 128) { A = A1; O = O1; KD = 1024; u = bidx * 256 + threadIdx.x; }
  else            { A = A2; O = O2; KD = 256;  u = (bidx - 128) * 256 + threadIdx.x; }
  const int t    = u >> 11;                 // K-tile (2048 units of 16 B per tile)
  const int r    = u & 2047;
  const int wm   = r >> 9, kk = (r >> 8) & 1, mi = (r >> 6) & 3, lane = r & 63;
  const int row  = wm * 64 + mi * 16 + (lane & 15);
  const int k    = t * 64 + kk * 32 + (lane >> 4) * 8;
  f4 v0 = *(const f4*)(A + (size_t)row * KD + k);
  f4 v1 = *(const f4*)(A + (size_t)row * KD + k + 4);
  us8 w = { f2bf(v0.v[0]), f2bf(v0.v[1]), f2bf(v0.v[2]), f2bf(v0.v[3]),
            f2bf(v1.v[0]), f2bf(v1.v[1]), f2bf(v1.v[2]), f2bf(v1.v[3]) };
  *(us8*)(O + (size_t)u * 8) = w;
}

// ============ GEMM1: xt[b][m][pix] = sum_k in_w[m][k]*x[b][k][pix] + bias[m] ====
// Contiguous staging (2 x 512-B segs/instr), cvt_pk+shfl transpose, swizzled LDS.
// B-prefetch depth 3 (rfA/rfB/rfC rotate): each B-load gets ~3 tile-periods
// (~1200 cyc) of cover vs ~900-1200 cyc loaded-HBM latency. FIFO discipline:
// A(t+1) issued BEFORE B(t+3); no vmem drain in the K-loop. R11 measured the
// depth-2 version at 73.8 us (floor ~46).
__global__ __launch_bounds__(512, 2)
void gemm1_kernel(const unsigned short* __restrict__ Afrag, const float* __restrict__ xb,
                  const float* __restrict__ bias, unsigned short* __restrict__ Cout,
                  float* __restrict__ ctx_sum)
{
  constexpr int NT = 16;
  __shared__ unsigned short B_sh[2][128 * 64];   // [pix] rows of 8 swizzled 16-B slots
  __shared__ float ctx_lds[1024];

  const int tid  = threadIdx.x;
  const int lane = tid & 63;
  const int wv   = tid >> 6;
  const int wm   = wv >> 1, wn = wv & 1;         // wave grid 4(M) x 2(N), tile 64x64
  const int lr   = lane & 15, lg = lane >> 4;
  const int hi   = lane >> 5, q = lane & 31;

  const int b    = blockIdx.x >> 5;
  const int pix0 = (blockIdx.x & 31) << 7;

  for (int i = tid; i < 1024; i += 512) ctx_lds[i] = 0.f;
  __syncthreads();

  f32x4 acc[4][4] = {};
  const size_t rowbase = ((size_t)b * CIN + 8 * wv + hi) * HW + pix0 + 4 * q;
  const char*  abase   = (const char*)Afrag + wm * 8192 + lane * 16;

  bf16x8 aA[8], aB[8];                           // A frag double-buffer (regs)
  f4 rfA[4], rfB[4], rfC[4];                     // B prefetch sets (depth 3)

  auto ISSUE_A = [&](int t, bf16x8* a) {
    const char* p = abase + t * 32768;
    #pragma unroll
    for (int i = 0; i < 8; ++i) a[i] = *(const bf16x8*)(p + i * 1024);
  };
  auto LOADB = [&](int t, f4* rf) {
    const float* p = xb + rowbase + (size_t)t * 64 * HW;
    #pragma unroll
    for (int i = 0; i < 4; ++i) rf[i] = *(const f4*)(p + (size_t)(2 * i) * HW);
  };
  auto WRITEB = [&](int sel, int t, f4* rf) {
    // fused context-pool partial sums (each x element staged once)
    #pragma unroll
    for (int i = 0; i < 4; ++i) {
      float s = rf[i].v[0] + rf[i].v[1] + rf[i].v[2] + rf[i].v[3];
      #pragma unroll
      for (int m = 1; m < 32; m <<= 1) s += __shfl_xor(s, m, 64);
      if (q == 0) atomicAdd(&ctx_lds[t * 64 + 8 * wv + 2 * i + hi], s);
    }
    unsigned int u[4][2];
    #pragma unroll
    for (int i = 0; i < 4; ++i) {
      asm("v_cvt_pk_bf16_f32 %0, %1, %2" : "=v"(u[i][0]) : "v"(rf[i].v[0]), "v"(rf[i].v[1]));
      asm("v_cvt_pk_bf16_f32 %0, %1, %2" : "=v"(u[i][1]) : "v"(rf[i].v[2]), "v"(rf[i].v[3]));
    }
    unsigned int w[4][2];
    #pragma unroll
    for (int i = 0; i < 4; ++i) {
      w[i][0] = __shfl_xor(u[i][0], 32, 64);
      w[i][1] = __shfl_xor(u[i][1], 32, 64);
    }
    // ch-ordered quad (offsets 0..3): hi=0 -> [u0,w0,u1,w1]; hi=1 -> [w2,u2,w3,u3]
    #pragma unroll
    for (int jj = 0; jj < 2; ++jj) {
      unsigned int A0 = hi ? w[2][jj] : u[0][jj];
      unsigned int A1 = hi ? u[2][jj] : w[0][jj];
      unsigned int A2 = hi ? w[3][jj] : u[1][jj];
      unsigned int A3 = hi ? u[3][jj] : w[1][jj];
      #pragma unroll
      for (int sub = 0; sub < 2; ++sub) {
        unsigned int lo, h2;
        if (sub == 0) { lo = (A0 & 0xffffu) | (A1 << 16);  h2 = (A2 & 0xffffu) | (A3 << 16); }
        else          { lo = (A0 >> 16) | (A1 & 0xffff0000u); h2 = (A2 >> 16) | (A3 & 0xffff0000u); }
        int p  = 4 * q + jj * 2 + sub;
        int fx = ((p >> 2) ^ p) & 7;
        int byte = p * 128 + (((wv ^ fx) & 7) << 4) + hi * 8;
        uint2 val; val.x = lo; val.y = h2;
        *(uint2*)((char*)B_sh[sel] + byte) = val;
      }
    }
  };
  auto COMPUTE = [&](int sel, bf16x8* a) {
    #pragma unroll
    for (int kk = 0; kk < 2; ++kk) {
      bf16x8 bfr[4];
      #pragma unroll
      for (int ni = 0; ni < 4; ++ni) {
        int pr = wn * 64 + ni * 16 + lr;
        int fx = ((pr >> 2) ^ pr) & 7;
        int byte = pr * 128 + ((((kk * 4 + lg) ^ fx) & 7) << 4);
        bfr[ni] = *(const bf16x8*)((const char*)B_sh[sel] + byte);
      }
      #pragma unroll
      for (int mi = 0; mi < 4; ++mi)
        #pragma unroll
        for (int ni = 0; ni < 4; ++ni)
          acc[mi][ni] = __builtin_amdgcn_mfma_f32_16x16x32_bf16(a[kk * 4 + mi], bfr[ni], acc[mi][ni], 0, 0, 0);
    }
  };
  // One pipeline step: consume rfc (tile t), refill rfc with tile t+3.
  auto STEP = [&](int t, f4* rfc, bf16x8* ac, bf16x8* an) {
    WRITEB(t & 1, t, rfc);                       // waits B(t) only (3 periods old)
    if (t + 1 < NT) ISSUE_A(t + 1, an);          // A older than B(t+3): FIFO discipline
    __builtin_amdgcn_sched_barrier(0);
    if (t + 3 < NT) LOADB(t + 3, rfc);
    LGWB();
    COMPUTE(t & 1, ac);                          // waits A(t); B(t+2),B(t+3) stay in flight
  };

  // prologue: A(0) + B(0),B(1),B(2) in flight
  ISSUE_A(0, aA);
  LOADB(0, rfA);
  LOADB(1, rfB);
  LOADB(2, rfC);

  STEP( 0, rfA, aA, aB);  STEP( 1, rfB, aB, aA);  STEP( 2, rfC, aA, aB);
  STEP( 3, rfA, aB, aA);  STEP( 4, rfB, aA, aB);  STEP( 5, rfC, aB, aA);
  STEP( 6, rfA, aA, aB);  STEP( 7, rfB, aB, aA);  STEP( 8, rfC, aA, aB);
  STEP( 9, rfA, aB, aA);  STEP(10, rfB, aA, aB);  STEP(11, rfC, aB, aA);
  STEP(12, rfA, aA, aB);  STEP(13, rfB, aB, aA);  STEP(14, rfC, aA, aB);
  STEP(15, rfA, aB, aA);

  // ---- epilogue: bias, bf16 store
  #pragma unroll
  for (int mi = 0; mi < 4; ++mi) {
    #pragma unroll
    for (int r = 0; r < 4; ++r) {
      int o = wm * 64 + mi * 16 + lg * 4 + r;   // C/D: col=lane&15, row=(lane>>4)*4+reg
      float bo = bias[o];
      #pragma unroll
      for (int ni = 0; ni < 4; ++ni) {
        int pix = pix0 + wn * 64 + ni * 16 + lr;
        Cout[((size_t)(b * HID + o)) * HW + pix] = f2bf(acc[mi][ni][r] + bo);
      }
    }
  }
  __syncthreads();
  for (int e = tid; e < 1024; e += 512)
    atomicAdd(&ctx_sum[(size_t)b * 1024 + e], ctx_lds[e]);
}

// ============ GEMM2 fused with depthwise conv ============
// out_trans[b][o][pix] = sum_ch out_w[o][ch] * dw[b][ch][pix] + out_b[o]
// dw computed on the fly from xt (LDS slab). lgkm-only K-loop barriers; BN
// epilogue ni-pre-summed (R10 win).
__global__ __launch_bounds__(512, 2)
void gemm2_fused_kernel(const unsigned short* __restrict__ Afrag,
                        const unsigned short* __restrict__ xt,
                        const float* __restrict__ kern, const float* __restrict__ bias,
                        unsigned short* __restrict__ Cout, float* __restrict__ bn_sums)
{
  constexpr int NT = 4;                          // KDIM 256 / 64
  __shared__ unsigned short B_sh[128 * 64];      // [pix][k] bf16, XOR-swizzled
  __shared__ unsigned short xs[64 * 260];        // [ch][4 rows][64], stride 260 (bank-spread)
  __shared__ float kf_s[72];
  __shared__ float bn_lds[512];

  const int tid  = threadIdx.x;
  const int lane = tid & 63;
  const int wv   = tid >> 6;
  const int wm   = wv >> 1, wn = wv & 1;
  const int lr   = lane & 15, lg = lane >> 4;

  const int b    = blockIdx.x >> 5;
  const int R    = blockIdx.x & 31;              // pixel tile: image rows 2R, 2R+1
  const int pix0 = R << 7;
  const int g0   = R << 1;

  if (tid < 512) bn_lds[tid] = 0.f;
  if (tid < 72)  kf_s[tid] = kern[b * 72 + tid];
  __syncthreads();

  f32x4 acc[4][4] = {};
  const int c4 = tid & 15, q = tid >> 4;
  const int prow  = q >> 4;                      // 0|1 image row within tile
  const int pcol4 = (q & 15) << 2;               // col base 0..60
  const int grp9  = (c4 >> 3) * 9;               // kf sub-index (plus 2t*9 per tile)

  const char* abase = (const char*)Afrag + wm * 8192 + lane * 16;

  bf16x8 aA[8];
  us8 rx[4];

  auto PREXS = [&](int t) {
    #pragma unroll
    for (int it = 0; it < 4; ++it) {
      int flat = it * 512 + tid;
      int ch = flat >> 5, r4 = (flat >> 3) & 3, c8 = flat & 7;
      int grow = g0 - 1 + r4;
      if ((unsigned)grow < 64u) {
        rx[it] = *(const us8*)(xt + ((size_t)(b * HID + t * 64 + ch) << 12) + grow * 64 + c8 * 8);
      } else {
        us8 z = {0, 0, 0, 0, 0, 0, 0, 0}; rx[it] = z;
      }
    }
  };
  auto WRXS = [&]() {
    #pragma unroll
    for (int it = 0; it < 4; ++it) {
      int flat = it * 512 + tid;
      int ch = flat >> 5, r4 = (flat >> 3) & 3, c8 = flat & 7;
      int o = ch * 260 + r4 * 64 + c8 * 8;
      *(us4*)(xs + o)     = *(const us4*)(&rx[it].v[0]);
      *(us4*)(xs + o + 4) = *(const us4*)(&rx[it].v[4]);
    }
  };
  auto ISSUE_A = [&](int t) {
    const char* p = abase + t * 32768;
    #pragma unroll
    for (int i = 0; i < 8; ++i) aA[i] = *(const bf16x8*)(p + i * 1024);
  };

  PREXS(0);
  ISSUE_A(0);

  for (int t = 0; t < NT; ++t) {
    WRXS();                                      // waits PREXS(t) only (FIFO: aA younger)
    LGWB();                                      // xs visible; vmem stays in flight
    if (t + 1 < NT) PREXS(t + 1);                // flies under dw-compute + MFMA
    // ---- depthwise 3x3 from xs -> B_sh (swizzled)
    {
      const float k0 = kf_s[2 * t * 9 + grp9 + 0], k1 = kf_s[2 * t * 9 + grp9 + 1], k2 = kf_s[2 * t * 9 + grp9 + 2];
      const float k3 = kf_s[2 * t * 9 + grp9 + 3], k4 = kf_s[2 * t * 9 + grp9 + 4], k5 = kf_s[2 * t * 9 + grp9 + 5];
      const float k6 = kf_s[2 * t * 9 + grp9 + 6], k7 = kf_s[2 * t * 9 + grp9 + 7], k8 = kf_s[2 * t * 9 + grp9 + 8];
      float dwv[4][4];
      #pragma unroll
      for (int i = 0; i < 4; ++i) {
        int ch = 4 * c4 + i;
        #pragma unroll
        for (int j = 0; j < 4; ++j) dwv[i][j] = 0.f;
        #pragma unroll
        for (int ky = 0; ky < 3; ++ky) {
          int ro = ch * 260 + (prow + ky) * 64;
          float v[6];
          unsigned int p0 = (pcol4 > 0)  ? *(const unsigned int*)(xs + ro + pcol4 - 2) : 0u;
          unsigned int p1 = *(const unsigned int*)(xs + ro + pcol4);
          unsigned int p2 = *(const unsigned int*)(xs + ro + pcol4 + 2);
          unsigned int p3 = (pcol4 < 60) ? *(const unsigned int*)(xs + ro + pcol4 + 4) : 0u;
          v[0] = bf2f((unsigned short)(p0 >> 16));
          v[1] = bf2f((unsigned short)(p1 & 0xffff));
          v[2] = bf2f((unsigned short)(p1 >> 16));
          v[3] = bf2f((unsigned short)(p2 & 0xffff));
          v[4] = bf2f((unsigned short)(p2 >> 16));
          v[5] = bf2f((unsigned short)(p3 & 0xffff));
          float ka = (ky == 0) ? k0 : (ky == 1) ? k3 : k6;
          float kb = (ky == 0) ? k1 : (ky == 1) ? k4 : k7;
          float kc = (ky == 0) ? k2 : (ky == 1) ? k5 : k8;
          #pragma unroll
          for (int j = 0; j < 4; ++j)
            dwv[i][j] += v[j] * ka + v[j + 1] * kb + v[j + 2] * kc;
        }
      }
      #pragma unroll
      for (int j = 0; j < 4; ++j) {
        int pix = 4 * q + j;
        us4 w = { f2bf(dwv[0][j]), f2bf(dwv[1][j]), f2bf(dwv[2][j]), f2bf(dwv[3][j]) };
        *(us4*)((char*)B_sh + pix * 128 + ((8 * c4) ^ ((pix & 7) << 4))) = w;
      }
    }
    LGWB();                                      // B_sh visible; PREXS(t+1) stays in flight
    // ---- MFMA
    #pragma unroll
    for (int kk = 0; kk < 2; ++kk) {
      bf16x8 bfr[4];
      #pragma unroll
      for (int ni = 0; ni < 4; ++ni) {
        int pr = wn * 64 + ni * 16 + lr;
        bfr[ni] = *(const bf16x8*)((const char*)B_sh + pr * 128 + ((((kk << 2) | lg) ^ (pr & 7)) << 4));
      }
      #pragma unroll
      for (int mi = 0; mi < 4; ++mi)
        #pragma unroll
        for (int ni = 0; ni < 4; ++ni)
          acc[mi][ni] = __builtin_amdgcn_mfma_f32_16x16x32_bf16(aA[kk * 4 + mi], bfr[ni], acc[mi][ni], 0, 0, 0);
    }
    if (t + 1 < NT) ISSUE_A(t + 1);              // after MFMA: aA regs free (single buffer)
  }

  // ---- epilogue: bias, bf16 store, BN stats (ni pre-summed: 4x fewer shuffles)
  #pragma unroll
  for (int mi = 0; mi < 4; ++mi) {
    #pragma unroll
    for (int r = 0; r < 4; ++r) {
      int o = wm * 64 + mi * 16 + lg * 4 + r;
      float bo = bias[o];
      float s = 0.f, s2 = 0.f;
      #pragma unroll
      for (int ni = 0; ni < 4; ++ni) {
        int pix = pix0 + wn * 64 + ni * 16 + lr;
        float val = acc[mi][ni][r] + bo;
        Cout[((size_t)(b * HID + o)) * HW + pix] = f2bf(val);
        s += val; s2 += val * val;
      }
      #pragma unroll
      for (int msk = 1; msk < 16; msk <<= 1) {
        s  += __shfl_xor(s,  msk, 64);
        s2 += __shfl_xor(s2, msk, 64);
      }
      if (lr == 0) { atomicAdd(&bn_lds[o], s); atomicAdd(&bn_lds[256 + o], s2); }
    }
  }
  __syncthreads();
  if (tid < 512) atomicAdd(&bn_sums[tid], bn_lds[tid]);
}

// wave-per-output FC layer: out[b][o] = act(scale * dot(in[b][:], w[o][:]) + bias[o])
template<int K, int N, bool RELU>
__global__ __launch_bounds__(256)
void fc_kernel(const float* __restrict__ in, const float* __restrict__ w,
               const float* __restrict__ bias, float* __restrict__ out, float scale)
{
  const int wid  = (blockIdx.x << 2) | (threadIdx.x >> 6);
  const int lane = threadIdx.x & 63;
  const int b = wid / N, o = wid - b * N;
  const float* ip = in + (size_t)b * K;
  const float* wp = w  + (size_t)o * K;
  float p = 0.f;
  #pragma unroll
  for (int k = 0; k < K / 64; ++k) p += ip[lane + k * 64] * wp[lane + k * 64];
  #pragma unroll
  for (int m = 1; m < 64; m <<= 1) p += __shfl_xor(p, m, 64);
  if (lane == 0) {
    float v = p * scale + bias[o];
    out[(size_t)b * N + o] = RELU ? fmaxf(v, 0.f) : v;
  }
}

// kernel-generator layers 2+3 fused: hddn (512, relu) in LDS, then kern (72).
// One block per sample b (16 blocks, 8 waves).
__global__ __launch_bounds__(512)
void kg_kernel(const float* __restrict__ ctxbuf, const float* __restrict__ kg_w1,
               const float* __restrict__ kg_b1, const float* __restrict__ kg_w2,
               const float* __restrict__ kg_b2, float* __restrict__ kern)
{
  __shared__ float ctx_s[256];
  __shared__ float hdn_s[512];
  const int b = blockIdx.x, tid = threadIdx.x, lane = tid & 63, wv = tid >> 6;
  if (tid < 256) ctx_s[tid] = ctxbuf[b * 256 + tid];
  __syncthreads();
  #pragma unroll 4
  for (int j = wv * 64; j < wv * 64 + 64; ++j) {
    const float* wp = kg_w1 + (size_t)j * 256;
    float p = 0.f;
    #pragma unroll
    for (int k = 0; k < 4; ++k) p += ctx_s[lane + k * 64] * wp[lane + k * 64];
    #pragma unroll
    for (int m = 1; m < 64; m <<= 1) p += __shfl_xor(p, m, 64);
    if (lane == 0) hdn_s[j] = fmaxf(p + kg_b1[j], 0.f);
  }
  __syncthreads();
  for (int j = wv; j < 72; j += 8) {
    const float* wp = kg_w2 + (size_t)j * 512;
    float p = 0.f;
    #pragma unroll
    for (int k = 0; k < 8; ++k) p += hdn_s[lane + k * 64] * wp[lane + k * 64];
    #pragma unroll
    for (int m = 1; m < 64; m <<= 1) p += __shfl_xor(p, m, 64);
    if (lane == 0) kern[b * 72 + j] = p + kg_b2[j];
  }
}

// out = xt + scale[o]*ot + shift[o]; BN finalize folded in (per-block from bn_sums)
__global__ __launch_bounds__(256)
void final_kernel(const unsigned short* __restrict__ xt, const unsigned short* __restrict__ ot,
                  const float* __restrict__ bn_sums, const float* __restrict__ gamma,
                  const float* __restrict__ beta, float* __restrict__ out)
{
  __shared__ float sc_s[256], sh_s[256];
  {
    int t = threadIdx.x;
    const float inv_n = 1.f / 65536.f;          // B*H*W
    float m  = bn_sums[t] * inv_n;
    float v  = bn_sums[256 + t] * inv_n - m * m;
    float sc = gamma[t] * rsqrtf(v + 1e-5f);
    sc_s[t] = sc;
    sh_s[t] = beta[t] - m * sc;
  }
  __syncthreads();
  int g = blockIdx.x * 256 + threadIdx.x;       // group of 4 elements
  const int stride = 4096 * 256;
  #pragma unroll
  for (int it = 0; it < 4; ++it, g += stride) {
    int o = (g >> 10) & 255;
    us4 a = ((const us4*)xt)[g];
    us4 c = ((const us4*)ot)[g];
    float s = sc_s[o], h = sh_s[o];
    f4 r;
    #pragma unroll
    for (int j = 0; j < 4; ++j) r.v[j] = bf2f(a.v[j]) + s * bf2f(c.v[j]) + h;
    *(f4*)(out + (size_t)g * 4) = r;
  }
}

extern "C" void kernel_launch(void* const* d_in, const int* in_sizes, int n_in,
                              void* d_out, int out_size, void* d_ws, size_t ws_size,
                              hipStream_t stream)
{
  const float* x     = (const float*)d_in[0];
  const float* ctx_w = (const float*)d_in[1];
  const float* ctx_b = (const float*)d_in[2];
  const float* kg_w1 = (const float*)d_in[3];
  const float* kg_b1 = (const float*)d_in[4];
  const float* kg_w2 = (const float*)d_in[5];
  const float* kg_b2 = (const float*)d_in[6];
  const float* in_w  = (const float*)d_in[7];
  const float* in_b  = (const float*)d_in[8];
  const float* out_w = (const float*)d_in[9];
  const float* out_b = (const float*)d_in[10];
  const float* gamma = (const float*)d_in[11];
  const float* beta  = (const float*)d_in[12];
  float* out = (float*)d_out;

  char* ws = (char*)d_ws;
  unsigned short* xt = (unsigned short*)ws;                  // 32 MiB bf16 xt
  unsigned short* ot = (unsigned short*)(ws + 33554432);     // 32 MiB bf16 out_trans
  float* ctx_sum = (float*)(ws + 67108864);                  // [16][1024]
  float* bn_sums = ctx_sum + 16384;                          // [512] (zeroed by prep)
  float* kern    = bn_sums + 512;                            // [16][72]
  float* ctxbuf  = kern + 1152;                              // [16][256]
  unsigned short* afrag1 = (unsigned short*)(ws + 67108864 + 131072);            // 512 KiB
  unsigned short* afrag2 = (unsigned short*)(ws + 67108864 + 131072 + 524288);   // 128 KiB

  prep_kernel<<<226, 256, 0, stream>>>(in_w, afrag1, out_w, afrag2, ctx_sum);
  gemm1_kernel<<<512, 512, 0, stream>>>(afrag1, x, in_b, xt, ctx_sum);
  fc_kernel<1024, 256, true><<<1024, 256, 0, stream>>>(ctx_sum, ctx_w, ctx_b, ctxbuf, 1.f / 4096.f);
  kg_kernel<<<16, 512, 0, stream>>>(ctxbuf, kg_w1, kg_b1, kg_w2, kg_b2, kern);
  gemm2_fused_kernel<<<512, 512, 0, stream>>>(afrag2, xt, kern, out_b, ot, bn_sums);
  final_kernel<<<4096, 256, 0, stream>>>(xt, ot, bn_sums, gamma, beta, out);
}

// Round 15
// 218.888 us; speedup vs baseline: 1.0085x; 1.0085x over previous
//
#include <hip/hip_runtime.h>

#define BATCH 16
#define CIN   1024
#define HID   256
#define HW    4096

typedef __attribute__((ext_vector_type(8))) short bf16x8;
typedef __attribute__((ext_vector_type(4))) float f32x4;

struct __align__(16) f4  { float v[4]; };
struct __align__(8)  us4 { unsigned short v[4]; };
struct __align__(16) us8 { unsigned short v[8]; };

__device__ __forceinline__ float bf2f(unsigned short u) {
  unsigned int x = ((unsigned int)u) << 16;
  return __builtin_bit_cast(float, x);
}
__device__ __forceinline__ unsigned short f2bf(float f) {
  unsigned int u = __builtin_bit_cast(unsigned int, f);
  u += 0x7fff + ((u >> 16) & 1);            // round-to-nearest-even
  return (unsigned short)(u >> 16);
}

// lgkm-only barrier: drain ds ops, leave ALL vmem prefetch in flight
#define LGWB() do { __builtin_amdgcn_sched_barrier(0); \
  asm volatile("s_waitcnt lgkmcnt(0)" ::: "memory"); \
  __builtin_amdgcn_s_barrier(); \
  __builtin_amdgcn_sched_barrier(0); } while (0)

// Pre-convert fp32 [256][KD] weights into per-lane bf16 MFMA A-fragments:
// unit u -> [tile][wm][kk][mi][lane], 16 B each. Trailing blocks zero ctx/bn sums.
__global__ __launch_bounds__(256)
void prep_kernel(const float* __restrict__ A1, unsigned short* __restrict__ O1,
                 const float* __restrict__ A2, unsigned short* __restrict__ O2,
                 float* __restrict__ zbuf)
{
  const int bidx = blockIdx.x;
  if (bidx >= 160) {                        // zero ctx_sum[16384] + bn_sums[512]
    int idx = (bidx - 160) * 256 + threadIdx.x;
    if (idx < 16896) zbuf[idx] = 0.f;
    return;
  }
  const float* A; unsigned short* O; int KD, u;
  if (bidx < 128) { A = A1; O = O1; KD = 1024; u = bidx * 256 + threadIdx.x; }
  else            { A = A2; O = O2; KD = 256;  u = (bidx - 128) * 256 + threadIdx.x; }
  const int t    = u >> 11;                 // K-tile (2048 units of 16 B per tile)
  const int r    = u & 2047;
  const int wm   = r >> 9, kk = (r >> 8) & 1, mi = (r >> 6) & 3, lane = r & 63;
  const int row  = wm * 64 + mi * 16 + (lane & 15);
  const int k    = t * 64 + kk * 32 + (lane >> 4) * 8;
  f4 v0 = *(const f4*)(A + (size_t)row * KD + k);
  f4 v1 = *(const f4*)(A + (size_t)row * KD + k + 4);
  us8 w = { f2bf(v0.v[0]), f2bf(v0.v[1]), f2bf(v0.v[2]), f2bf(v0.v[3]),
            f2bf(v1.v[0]), f2bf(v1.v[1]), f2bf(v1.v[2]), f2bf(v1.v[3]) };
  *(us8*)(O + (size_t)u * 8) = w;
}

// ============ GEMM1: xt[b][m][pix] = sum_k in_w[m][k]*x[b][k][pix] + bias[m] ====
// R12 configuration (measured 73.8 us standalone): contiguous staging, cvt_pk+shfl
// transpose, swizzled LDS, depth-2 B prefetch, FIFO discipline, rolled loop.
__global__ __launch_bounds__(512, 2)
void gemm1_kernel(const unsigned short* __restrict__ Afrag, const float* __restrict__ xb,
                  const float* __restrict__ bias, unsigned short* __restrict__ Cout,
                  float* __restrict__ ctx_sum)
{
  constexpr int NT = 16;
  __shared__ unsigned short B_sh[2][128 * 64];   // [pix] rows of 8 swizzled 16-B slots
  __shared__ float ctx_lds[1024];

  const int tid  = threadIdx.x;
  const int lane = tid & 63;
  const int wv   = tid >> 6;
  const int wm   = wv >> 1, wn = wv & 1;         // wave grid 4(M) x 2(N), tile 64x64
  const int lr   = lane & 15, lg = lane >> 4;
  const int hi   = lane >> 5, q = lane & 31;

  const int b    = blockIdx.x >> 5;
  const int pix0 = (blockIdx.x & 31) << 7;

  for (int i = tid; i < 1024; i += 512) ctx_lds[i] = 0.f;
  __syncthreads();

  f32x4 acc[4][4] = {};
  const size_t rowbase = ((size_t)b * CIN + 8 * wv + hi) * HW + pix0 + 4 * q;
  const char*  abase   = (const char*)Afrag + wm * 8192 + lane * 16;

  bf16x8 aA[8], aB[8];                           // A frag double-buffer (regs)
  f4 rfA[4], rfB[4];                             // B prefetch sets

  auto ISSUE_A = [&](int t, bf16x8* a) {
    const char* p = abase + t * 32768;
    #pragma unroll
    for (int i = 0; i < 8; ++i) a[i] = *(const bf16x8*)(p + i * 1024);
  };
  auto LOADB = [&](int t, f4* rf) {
    const float* p = xb + rowbase + (size_t)t * 64 * HW;
    #pragma unroll
    for (int i = 0; i < 4; ++i) rf[i] = *(const f4*)(p + (size_t)(2 * i) * HW);
  };
  auto WRITEB = [&](int sel, int t, f4* rf) {
    // fused context-pool partial sums (each x element staged once)
    #pragma unroll
    for (int i = 0; i < 4; ++i) {
      float s = rf[i].v[0] + rf[i].v[1] + rf[i].v[2] + rf[i].v[3];
      #pragma unroll
      for (int m = 1; m < 32; m <<= 1) s += __shfl_xor(s, m, 64);
      if (q == 0) atomicAdd(&ctx_lds[t * 64 + 8 * wv + 2 * i + hi], s);
    }
    unsigned int u[4][2];
    #pragma unroll
    for (int i = 0; i < 4; ++i) {
      asm("v_cvt_pk_bf16_f32 %0, %1, %2" : "=v"(u[i][0]) : "v"(rf[i].v[0]), "v"(rf[i].v[1]));
      asm("v_cvt_pk_bf16_f32 %0, %1, %2" : "=v"(u[i][1]) : "v"(rf[i].v[2]), "v"(rf[i].v[3]));
    }
    unsigned int w[4][2];
    #pragma unroll
    for (int i = 0; i < 4; ++i) {
      w[i][0] = __shfl_xor(u[i][0], 32, 64);
      w[i][1] = __shfl_xor(u[i][1], 32, 64);
    }
    // ch-ordered quad (offsets 0..3): hi=0 -> [u0,w0,u1,w1]; hi=1 -> [w2,u2,w3,u3]
    #pragma unroll
    for (int jj = 0; jj < 2; ++jj) {
      unsigned int A0 = hi ? w[2][jj] : u[0][jj];
      unsigned int A1 = hi ? u[2][jj] : w[0][jj];
      unsigned int A2 = hi ? w[3][jj] : u[1][jj];
      unsigned int A3 = hi ? u[3][jj] : w[1][jj];
      #pragma unroll
      for (int sub = 0; sub < 2; ++sub) {
        unsigned int lo, h2;
        if (sub == 0) { lo = (A0 & 0xffffu) | (A1 << 16);  h2 = (A2 & 0xffffu) | (A3 << 16); }
        else          { lo = (A0 >> 16) | (A1 & 0xffff0000u); h2 = (A2 >> 16) | (A3 & 0xffff0000u); }
        int p  = 4 * q + jj * 2 + sub;
        int fx = ((p >> 2) ^ p) & 7;
        int byte = p * 128 + (((wv ^ fx) & 7) << 4) + hi * 8;
        uint2 val; val.x = lo; val.y = h2;
        *(uint2*)((char*)B_sh[sel] + byte) = val;
      }
    }
  };
  auto COMPUTE = [&](int sel, bf16x8* a) {
    #pragma unroll
    for (int kk = 0; kk < 2; ++kk) {
      bf16x8 bfr[4];
      #pragma unroll
      for (int ni = 0; ni < 4; ++ni) {
        int pr = wn * 64 + ni * 16 + lr;
        int fx = ((pr >> 2) ^ pr) & 7;
        int byte = pr * 128 + ((((kk * 4 + lg) ^ fx) & 7) << 4);
        bfr[ni] = *(const bf16x8*)((const char*)B_sh[sel] + byte);
      }
      #pragma unroll
      for (int mi = 0; mi < 4; ++mi)
        #pragma unroll
        for (int ni = 0; ni < 4; ++ni)
          acc[mi][ni] = __builtin_amdgcn_mfma_f32_16x16x32_bf16(a[kk * 4 + mi], bfr[ni], acc[mi][ni], 0, 0, 0);
    }
  };

  // prologue: A(0) + B(0),B(1) in flight
  ISSUE_A(0, aA);
  LOADB(0, rfA);
  LOADB(1, rfB);

  #pragma unroll
  for (int t = 0; t < NT; t += 2) {
    // ---- half 1: tile t (B_sh[0], aA). A-issue BEFORE B-issue (FIFO discipline).
    WRITEB(0, t, rfA);
    ISSUE_A(t + 1, aB);
    __builtin_amdgcn_sched_barrier(0);           // pin: aB loads older than LOADB(t+2)
    if (t + 2 < NT) LOADB(t + 2, rfA);
    LGWB();
    COMPUTE(0, aA);                              // waits aA only; B prefetch stays in flight
    // ---- half 2: tile t+1 (B_sh[1], aB)
    WRITEB(1, t + 1, rfB);
    if (t + 2 < NT) ISSUE_A(t + 2, aA);
    __builtin_amdgcn_sched_barrier(0);           // pin: aA loads older than LOADB(t+3)
    if (t + 3 < NT) LOADB(t + 3, rfB);
    LGWB();
    COMPUTE(1, aB);                              // waits aB only
  }

  // ---- epilogue: bias, bf16 store
  #pragma unroll
  for (int mi = 0; mi < 4; ++mi) {
    #pragma unroll
    for (int r = 0; r < 4; ++r) {
      int o = wm * 64 + mi * 16 + lg * 4 + r;   // C/D: col=lane&15, row=(lane>>4)*4+reg
      float bo = bias[o];
      #pragma unroll
      for (int ni = 0; ni < 4; ++ni) {
        int pix = pix0 + wn * 64 + ni * 16 + lr;
        Cout[((size_t)(b * HID + o)) * HW + pix] = f2bf(acc[mi][ni][r] + bo);
      }
    }
  }
  __syncthreads();
  for (int e = tid; e < 1024; e += 512)
    atomicAdd(&ctx_sum[(size_t)b * 1024 + e], ctx_lds[e]);
}

// ============ GEMM2 fused with depthwise conv ============
// out_trans[b][o][pix] = sum_ch out_w[o][ch] * dw[b][ch][pix] + out_b[o]
// dw computed on the fly from xt (LDS slab). lgkm-only K-loop barriers; BN
// epilogue ni-pre-summed (R10 win).
__global__ __launch_bounds__(512, 2)
void gemm2_fused_kernel(const unsigned short* __restrict__ Afrag,
                        const unsigned short* __restrict__ xt,
                        const float* __restrict__ kern, const float* __restrict__ bias,
                        unsigned short* __restrict__ Cout, float* __restrict__ bn_sums)
{
  constexpr int NT = 4;                          // KDIM 256 / 64
  __shared__ unsigned short B_sh[128 * 64];      // [pix][k] bf16, XOR-swizzled
  __shared__ unsigned short xs[64 * 260];        // [ch][4 rows][64], stride 260 (bank-spread)
  __shared__ float kf_s[72];
  __shared__ float bn_lds[512];

  const int tid  = threadIdx.x;
  const int lane = tid & 63;
  const int wv   = tid >> 6;
  const int wm   = wv >> 1, wn = wv & 1;
  const int lr   = lane & 15, lg = lane >> 4;

  const int b    = blockIdx.x >> 5;
  const int R    = blockIdx.x & 31;              // pixel tile: image rows 2R, 2R+1
  const int pix0 = R << 7;
  const int g0   = R << 1;

  if (tid < 512) bn_lds[tid] = 0.f;
  if (tid < 72)  kf_s[tid] = kern[b * 72 + tid];
  __syncthreads();

  f32x4 acc[4][4] = {};
  const int c4 = tid & 15, q = tid >> 4;
  const int prow  = q >> 4;                      // 0|1 image row within tile
  const int pcol4 = (q & 15) << 2;               // col base 0..60
  const int grp9  = (c4 >> 3) * 9;               // kf sub-index (plus 2t*9 per tile)

  const char* abase = (const char*)Afrag + wm * 8192 + lane * 16;

  bf16x8 aA[8];
  us8 rx[4];

  auto PREXS = [&](int t) {
    #pragma unroll
    for (int it = 0; it < 4; ++it) {
      int flat = it * 512 + tid;
      int ch = flat >> 5, r4 = (flat >> 3) & 3, c8 = flat & 7;
      int grow = g0 - 1 + r4;
      if ((unsigned)grow < 64u) {
        rx[it] = *(const us8*)(xt + ((size_t)(b * HID + t * 64 + ch) << 12) + grow * 64 + c8 * 8);
      } else {
        us8 z = {0, 0, 0, 0, 0, 0, 0, 0}; rx[it] = z;
      }
    }
  };
  auto WRXS = [&]() {
    #pragma unroll
    for (int it = 0; it < 4; ++it) {
      int flat = it * 512 + tid;
      int ch = flat >> 5, r4 = (flat >> 3) & 3, c8 = flat & 7;
      int o = ch * 260 + r4 * 64 + c8 * 8;
      *(us4*)(xs + o)     = *(const us4*)(&rx[it].v[0]);
      *(us4*)(xs + o + 4) = *(const us4*)(&rx[it].v[4]);
    }
  };
  auto ISSUE_A = [&](int t) {
    const char* p = abase + t * 32768;
    #pragma unroll
    for (int i = 0; i < 8; ++i) aA[i] = *(const bf16x8*)(p + i * 1024);
  };

  PREXS(0);
  ISSUE_A(0);

  for (int t = 0; t < NT; ++t) {
    WRXS();                                      // waits PREXS(t) only (FIFO: aA younger)
    LGWB();                                      // xs visible; vmem stays in flight
    if (t + 1 < NT) PREXS(t + 1);                // flies under dw-compute + MFMA
    // ---- depthwise 3x3 from xs -> B_sh (swizzled)
    {
      const float k0 = kf_s[2 * t * 9 + grp9 + 0], k1 = kf_s[2 * t * 9 + grp9 + 1], k2 = kf_s[2 * t * 9 + grp9 + 2];
      const float k3 = kf_s[2 * t * 9 + grp9 + 3], k4 = kf_s[2 * t * 9 + grp9 + 4], k5 = kf_s[2 * t * 9 + grp9 + 5];
      const float k6 = kf_s[2 * t * 9 + grp9 + 6], k7 = kf_s[2 * t * 9 + grp9 + 7], k8 = kf_s[2 * t * 9 + grp9 + 8];
      float dwv[4][4];
      #pragma unroll
      for (int i = 0; i < 4; ++i) {
        int ch = 4 * c4 + i;
        #pragma unroll
        for (int j = 0; j < 4; ++j) dwv[i][j] = 0.f;
        #pragma unroll
        for (int ky = 0; ky < 3; ++ky) {
          int ro = ch * 260 + (prow + ky) * 64;
          float v[6];
          unsigned int p0 = (pcol4 > 0)  ? *(const unsigned int*)(xs + ro + pcol4 - 2) : 0u;
          unsigned int p1 = *(const unsigned int*)(xs + ro + pcol4);
          unsigned int p2 = *(const unsigned int*)(xs + ro + pcol4 + 2);
          unsigned int p3 = (pcol4 < 60) ? *(const unsigned int*)(xs + ro + pcol4 + 4) : 0u;
          v[0] = bf2f((unsigned short)(p0 >> 16));
          v[1] = bf2f((unsigned short)(p1 & 0xffff));
          v[2] = bf2f((unsigned short)(p1 >> 16));
          v[3] = bf2f((unsigned short)(p2 & 0xffff));
          v[4] = bf2f((unsigned short)(p2 >> 16));
          v[5] = bf2f((unsigned short)(p3 & 0xffff));
          float ka = (ky == 0) ? k0 : (ky == 1) ? k3 : k6;
          float kb = (ky == 0) ? k1 : (ky == 1) ? k4 : k7;
          float kc = (ky == 0) ? k2 : (ky == 1) ? k5 : k8;
          #pragma unroll
          for (int j = 0; j < 4; ++j)
            dwv[i][j] += v[j] * ka + v[j + 1] * kb + v[j + 2] * kc;
        }
      }
      #pragma unroll
      for (int j = 0; j < 4; ++j) {
        int pix = 4 * q + j;
        us4 w = { f2bf(dwv[0][j]), f2bf(dwv[1][j]), f2bf(dwv[2][j]), f2bf(dwv[3][j]) };
        *(us4*)((char*)B_sh + pix * 128 + ((8 * c4) ^ ((pix & 7) << 4))) = w;
      }
    }
    LGWB();                                      // B_sh visible; PREXS(t+1) stays in flight
    // ---- MFMA
    #pragma unroll
    for (int kk = 0; kk < 2; ++kk) {
      bf16x8 bfr[4];
      #pragma unroll
      for (int ni = 0; ni < 4; ++ni) {
        int pr = wn * 64 + ni * 16 + lr;
        bfr[ni] = *(const bf16x8*)((const char*)B_sh + pr * 128 + ((((kk << 2) | lg) ^ (pr & 7)) << 4));
      }
      #pragma unroll
      for (int mi = 0; mi < 4; ++mi)
        #pragma unroll
        for (int ni = 0; ni < 4; ++ni)
          acc[mi][ni] = __builtin_amdgcn_mfma_f32_16x16x32_bf16(aA[kk * 4 + mi], bfr[ni], acc[mi][ni], 0, 0, 0);
    }
    if (t + 1 < NT) ISSUE_A(t + 1);              // after MFMA: aA regs free (single buffer)
  }

  // ---- epilogue: bias, bf16 store, BN stats (ni pre-summed: 4x fewer shuffles)
  #pragma unroll
  for (int mi = 0; mi < 4; ++mi) {
    #pragma unroll
    for (int r = 0; r < 4; ++r) {
      int o = wm * 64 + mi * 16 + lg * 4 + r;
      float bo = bias[o];
      float s = 0.f, s2 = 0.f;
      #pragma unroll
      for (int ni = 0; ni < 4; ++ni) {
        int pix = pix0 + wn * 64 + ni * 16 + lr;
        float val = acc[mi][ni][r] + bo;
        Cout[((size_t)(b * HID + o)) * HW + pix] = f2bf(val);
        s += val; s2 += val * val;
      }
      #pragma unroll
      for (int msk = 1; msk < 16; msk <<= 1) {
        s  += __shfl_xor(s,  msk, 64);
        s2 += __shfl_xor(s2, msk, 64);
      }
      if (lr == 0) { atomicAdd(&bn_lds[o], s); atomicAdd(&bn_lds[256 + o], s2); }
    }
  }
  __syncthreads();
  if (tid < 512) atomicAdd(&bn_sums[tid], bn_lds[tid]);
}

// wave-per-output FC layer: out[b][o] = act(scale * dot(in[b][:], w[o][:]) + bias[o])
template<int K, int N, bool RELU>
__global__ __launch_bounds__(256)
void fc_kernel(const float* __restrict__ in, const float* __restrict__ w,
               const float* __restrict__ bias, float* __restrict__ out, float scale)
{
  const int wid  = (blockIdx.x << 2) | (threadIdx.x >> 6);
  const int lane = threadIdx.x & 63;
  const int b = wid / N, o = wid - b * N;
  const float* ip = in + (size_t)b * K;
  const float* wp = w  + (size_t)o * K;
  float p = 0.f;
  #pragma unroll
  for (int k = 0; k < K / 64; ++k) p += ip[lane + k * 64] * wp[lane + k * 64];
  #pragma unroll
  for (int m = 1; m < 64; m <<= 1) p += __shfl_xor(p, m, 64);
  if (lane == 0) {
    float v = p * scale + bias[o];
    out[(size_t)b * N + o] = RELU ? fmaxf(v, 0.f) : v;
  }
}

// kernel-generator layers 2+3 fused: hddn (512, relu) in LDS, then kern (72).
// One block per sample b (16 blocks, 8 waves).
__global__ __launch_bounds__(512)
void kg_kernel(const float* __restrict__ ctxbuf, const float* __restrict__ kg_w1,
               const float* __restrict__ kg_b1, const float* __restrict__ kg_w2,
               const float* __restrict__ kg_b2, float* __restrict__ kern)
{
  __shared__ float ctx_s[256];
  __shared__ float hdn_s[512];
  const int b = blockIdx.x, tid = threadIdx.x, lane = tid & 63, wv = tid >> 6;
  if (tid < 256) ctx_s[tid] = ctxbuf[b * 256 + tid];
  __syncthreads();
  #pragma unroll 4
  for (int j = wv * 64; j < wv * 64 + 64; ++j) {
    const float* wp = kg_w1 + (size_t)j * 256;
    float p = 0.f;
    #pragma unroll
    for (int k = 0; k < 4; ++k) p += ctx_s[lane + k * 64] * wp[lane + k * 64];
    #pragma unroll
    for (int m = 1; m < 64; m <<= 1) p += __shfl_xor(p, m, 64);
    if (lane == 0) hdn_s[j] = fmaxf(p + kg_b1[j], 0.f);
  }
  __syncthreads();
  for (int j = wv; j < 72; j += 8) {
    const float* wp = kg_w2 + (size_t)j * 512;
    float p = 0.f;
    #pragma unroll
    for (int k = 0; k < 8; ++k) p += hdn_s[lane + k * 64] * wp[lane + k * 64];
    #pragma unroll
    for (int m = 1; m < 64; m <<= 1) p += __shfl_xor(p, m, 64);
    if (lane == 0) kern[b * 72 + j] = p + kg_b2[j];
  }
}

// out = xt + scale[o]*ot + shift[o]; BN finalize folded in (per-block from bn_sums)
__global__ __launch_bounds__(256)
void final_kernel(const unsigned short* __restrict__ xt, const unsigned short* __restrict__ ot,
                  const float* __restrict__ bn_sums, const float* __restrict__ gamma,
                  const float* __restrict__ beta, float* __restrict__ out)
{
  __shared__ float sc_s[256], sh_s[256];
  {
    int t = threadIdx.x;
    const float inv_n = 1.f / 65536.f;          // B*H*W
    float m  = bn_sums[t] * inv_n;
    float v  = bn_sums[256 + t] * inv_n - m * m;
    float sc = gamma[t] * rsqrtf(v + 1e-5f);
    sc_s[t] = sc;
    sh_s[t] = beta[t] - m * sc;
  }
  __syncthreads();
  int g = blockIdx.x * 256 + threadIdx.x;       // group of 4 elements
  const int stride = 4096 * 256;
  #pragma unroll
  for (int it = 0; it < 4; ++it, g += stride) {
    int o = (g >> 10) & 255;
    us4 a = ((const us4*)xt)[g];
    us4 c = ((const us4*)ot)[g];
    float s = sc_s[o], h = sh_s[o];
    f4 r;
    #pragma unroll
    for (int j = 0; j < 4; ++j) r.v[j] = bf2f(a.v[j]) + s * bf2f(c.v[j]) + h;
    *(f4*)(out + (size_t)g * 4) = r;
  }
}

extern "C" void kernel_launch(void* const* d_in, const int* in_sizes, int n_in,
                              void* d_out, int out_size, void* d_ws, size_t ws_size,
                              hipStream_t stream)
{
  const float* x     = (const float*)d_in[0];
  const float* ctx_w = (const float*)d_in[1];
  const float* ctx_b = (const float*)d_in[2];
  const float* kg_w1 = (const float*)d_in[3];
  const float* kg_b1 = (const float*)d_in[4];
  const float* kg_w2 = (const float*)d_in[5];
  const float* kg_b2 = (const float*)d_in[6];
  const float* in_w  = (const float*)d_in[7];
  const float* in_b  = (const float*)d_in[8];
  const float* out_w = (const float*)d_in[9];
  const float* out_b = (const float*)d_in[10];
  const float* gamma = (const float*)d_in[11];
  const float* beta  = (const float*)d_in[12];
  float* out = (float*)d_out;

  char* ws = (char*)d_ws;
  unsigned short* xt = (unsigned short*)ws;                  // 32 MiB bf16 xt
  unsigned short* ot = (unsigned short*)(ws + 33554432);     // 32 MiB bf16 out_trans
  float* ctx_sum = (float*)(ws + 67108864);                  // [16][1024]
  float* bn_sums = ctx_sum + 16384;                          // [512] (zeroed by prep)
  float* kern    = bn_sums + 512;                            // [16][72]
  float* ctxbuf  = kern + 1152;                              // [16][256]
  unsigned short* afrag1 = (unsigned short*)(ws + 67108864 + 131072);            // 512 KiB
  unsigned short* afrag2 = (unsigned short*)(ws + 67108864 + 131072 + 524288);   // 128 KiB

  prep_kernel<<<226, 256, 0, stream>>>(in_w, afrag1, out_w, afrag2, ctx_sum);
  gemm1_kernel<<<512, 512, 0, stream>>>(afrag1, x, in_b, xt, ctx_sum);
  fc_kernel<1024, 256, true><<<1024, 256, 0, stream>>>(ctx_sum, ctx_w, ctx_b, ctxbuf, 1.f / 4096.f);
  kg_kernel<<<16, 512, 0, stream>>>(ctxbuf, kg_w1, kg_b1, kg_w2, kg_b2, kern);
  gemm2_fused_kernel<<<512, 512, 0, stream>>>(afrag2, xt, kern, out_b, ot, bn_sums);
  final_kernel<<<4096, 256, 0, stream>>>(xt, ot, bn_sums, gamma, beta, out);
}

// Round 16
// 164.080 us; speedup vs baseline: 1.3454x; 1.3340x over previous
//
#include <hip/hip_runtime.h>

#define BATCH 16
#define CIN   1024
#define HID   256
#define HW    4096

typedef __attribute__((ext_vector_type(8))) short bf16x8;
typedef __attribute__((ext_vector_type(4))) float f32x4;

struct __align__(16) f4  { float v[4]; };
struct __align__(8)  us4 { unsigned short v[4]; };
struct __align__(16) us8 { unsigned short v[8]; };

__device__ __forceinline__ float bf2f(unsigned short u) {
  unsigned int x = ((unsigned int)u) << 16;
  return __builtin_bit_cast(float, x);
}
__device__ __forceinline__ unsigned short f2bf(float f) {
  unsigned int u = __builtin_bit_cast(unsigned int, f);
  u += 0x7fff + ((u >> 16) & 1);            // round-to-nearest-even
  return (unsigned short)(u >> 16);
}

// lgkm-only barrier: drain ds ops, leave ALL vmem prefetch in flight
#define LGWB() do { __builtin_amdgcn_sched_barrier(0); \
  asm volatile("s_waitcnt lgkmcnt(0)" ::: "memory"); \
  __builtin_amdgcn_s_barrier(); \
  __builtin_amdgcn_sched_barrier(0); } while (0)

// Pre-convert fp32 [256][KD] weights into per-lane bf16 MFMA A-fragments:
// unit u -> [tile][wm][kk][mi][lane], 16 B each. Trailing blocks zero ctx/bn sums.
__global__ __launch_bounds__(256)
void prep_kernel(const float* __restrict__ A1, unsigned short* __restrict__ O1,
                 const float* __restrict__ A2, unsigned short* __restrict__ O2,
                 float* __restrict__ zbuf)
{
  const int bidx = blockIdx.x;
  if (bidx >= 160) {                        // zero ctx_sum[16384] + bn_sums[512]
    int idx = (bidx - 160) * 256 + threadIdx.x;
    if (idx < 16896) zbuf[idx] = 0.f;
    return;
  }
  const float* A; unsigned short* O; int KD, u;
  if (bidx < 128) { A = A1; O = O1; KD = 1024; u = bidx * 256 + threadIdx.x; }
  else            { A = A2; O = O2; KD = 256;  u = (bidx - 128) * 256 + threadIdx.x; }
  const int t    = u >> 11;                 // K-tile (2048 units of 16 B per tile)
  const int r    = u & 2047;
  const int wm   = r >> 9, kk = (r >> 8) & 1, mi = (r >> 6) & 3, lane = r & 63;
  const int row  = wm * 64 + mi * 16 + (lane & 15);
  const int k    = t * 64 + kk * 32 + (lane >> 4) * 8;
  f4 v0 = *(const f4*)(A + (size_t)row * KD + k);
  f4 v1 = *(const f4*)(A + (size_t)row * KD + k + 4);
  us8 w = { f2bf(v0.v[0]), f2bf(v0.v[1]), f2bf(v0.v[2]), f2bf(v0.v[3]),
            f2bf(v1.v[0]), f2bf(v1.v[1]), f2bf(v1.v[2]), f2bf(v1.v[3]) };
  *(us8*)(O + (size_t)u * 8) = w;
}

// ============ GEMM1: xt[b][m][pix] = sum_k in_w[m][k]*x[b][k][pix] + bias[m] ====
// R12 configuration (measured 73.8 us standalone): contiguous staging, cvt_pk+shfl
// transpose, swizzled LDS, depth-2 B prefetch, FIFO discipline, rolled loop.
__global__ __launch_bounds__(512, 2)
void gemm1_kernel(const unsigned short* __restrict__ Afrag, const float* __restrict__ xb,
                  const float* __restrict__ bias, unsigned short* __restrict__ Cout,
                  float* __restrict__ ctx_sum)
{
  constexpr int NT = 16;
  __shared__ unsigned short B_sh[2][128 * 64];   // [pix] rows of 8 swizzled 16-B slots
  __shared__ float ctx_lds[1024];

  const int tid  = threadIdx.x;
  const int lane = tid & 63;
  const int wv   = tid >> 6;
  const int wm   = wv >> 1, wn = wv & 1;         // wave grid 4(M) x 2(N), tile 64x64
  const int lr   = lane & 15, lg = lane >> 4;
  const int hi   = lane >> 5, q = lane & 31;

  const int b    = blockIdx.x >> 5;
  const int pix0 = (blockIdx.x & 31) << 7;

  for (int i = tid; i < 1024; i += 512) ctx_lds[i] = 0.f;
  __syncthreads();

  f32x4 acc[4][4] = {};
  const size_t rowbase = ((size_t)b * CIN + 8 * wv + hi) * HW + pix0 + 4 * q;
  const char*  abase   = (const char*)Afrag + wm * 8192 + lane * 16;

  bf16x8 aA[8], aB[8];                           // A frag double-buffer (regs)
  f4 rfA[4], rfB[4];                             // B prefetch sets

  auto ISSUE_A = [&](int t, bf16x8* a) {
    const char* p = abase + t * 32768;
    #pragma unroll
    for (int i = 0; i < 8; ++i) a[i] = *(const bf16x8*)(p + i * 1024);
  };
  auto LOADB = [&](int t, f4* rf) {
    const float* p = xb + rowbase + (size_t)t * 64 * HW;
    #pragma unroll
    for (int i = 0; i < 4; ++i) rf[i] = *(const f4*)(p + (size_t)(2 * i) * HW);
  };
  auto WRITEB = [&](int sel, int t, f4* rf) {
    // fused context-pool partial sums (each x element staged once)
    #pragma unroll
    for (int i = 0; i < 4; ++i) {
      float s = rf[i].v[0] + rf[i].v[1] + rf[i].v[2] + rf[i].v[3];
      #pragma unroll
      for (int m = 1; m < 32; m <<= 1) s += __shfl_xor(s, m, 64);
      if (q == 0) atomicAdd(&ctx_lds[t * 64 + 8 * wv + 2 * i + hi], s);
    }
    unsigned int u[4][2];
    #pragma unroll
    for (int i = 0; i < 4; ++i) {
      asm("v_cvt_pk_bf16_f32 %0, %1, %2" : "=v"(u[i][0]) : "v"(rf[i].v[0]), "v"(rf[i].v[1]));
      asm("v_cvt_pk_bf16_f32 %0, %1, %2" : "=v"(u[i][1]) : "v"(rf[i].v[2]), "v"(rf[i].v[3]));
    }
    unsigned int w[4][2];
    #pragma unroll
    for (int i = 0; i < 4; ++i) {
      w[i][0] = __shfl_xor(u[i][0], 32, 64);
      w[i][1] = __shfl_xor(u[i][1], 32, 64);
    }
    // ch-ordered quad (offsets 0..3): hi=0 -> [u0,w0,u1,w1]; hi=1 -> [w2,u2,w3,u3]
    #pragma unroll
    for (int jj = 0; jj < 2; ++jj) {
      unsigned int A0 = hi ? w[2][jj] : u[0][jj];
      unsigned int A1 = hi ? u[2][jj] : w[0][jj];
      unsigned int A2 = hi ? w[3][jj] : u[1][jj];
      unsigned int A3 = hi ? u[3][jj] : w[1][jj];
      #pragma unroll
      for (int sub = 0; sub < 2; ++sub) {
        unsigned int lo, h2;
        if (sub == 0) { lo = (A0 & 0xffffu) | (A1 << 16);  h2 = (A2 & 0xffffu) | (A3 << 16); }
        else          { lo = (A0 >> 16) | (A1 & 0xffff0000u); h2 = (A2 >> 16) | (A3 & 0xffff0000u); }
        int p  = 4 * q + jj * 2 + sub;
        int fx = ((p >> 2) ^ p) & 7;
        int byte = p * 128 + (((wv ^ fx) & 7) << 4) + hi * 8;
        uint2 val; val.x = lo; val.y = h2;
        *(uint2*)((char*)B_sh[sel] + byte) = val;
      }
    }
  };
  auto COMPUTE = [&](int sel, bf16x8* a) {
    #pragma unroll
    for (int kk = 0; kk < 2; ++kk) {
      bf16x8 bfr[4];
      #pragma unroll
      for (int ni = 0; ni < 4; ++ni) {
        int pr = wn * 64 + ni * 16 + lr;
        int fx = ((pr >> 2) ^ pr) & 7;
        int byte = pr * 128 + ((((kk * 4 + lg) ^ fx) & 7) << 4);
        bfr[ni] = *(const bf16x8*)((const char*)B_sh[sel] + byte);
      }
      #pragma unroll
      for (int mi = 0; mi < 4; ++mi)
        #pragma unroll
        for (int ni = 0; ni < 4; ++ni)
          acc[mi][ni] = __builtin_amdgcn_mfma_f32_16x16x32_bf16(a[kk * 4 + mi], bfr[ni], acc[mi][ni], 0, 0, 0);
    }
  };

  // prologue: A(0) + B(0),B(1) in flight
  ISSUE_A(0, aA);
  LOADB(0, rfA);
  LOADB(1, rfB);

  #pragma unroll
  for (int t = 0; t < NT; t += 2) {
    // ---- half 1: tile t (B_sh[0], aA). A-issue BEFORE B-issue (FIFO discipline).
    WRITEB(0, t, rfA);
    ISSUE_A(t + 1, aB);
    __builtin_amdgcn_sched_barrier(0);           // pin: aB loads older than LOADB(t+2)
    if (t + 2 < NT) LOADB(t + 2, rfA);
    LGWB();
    COMPUTE(0, aA);                              // waits aA only; B prefetch stays in flight
    // ---- half 2: tile t+1 (B_sh[1], aB)
    WRITEB(1, t + 1, rfB);
    if (t + 2 < NT) ISSUE_A(t + 2, aA);
    __builtin_amdgcn_sched_barrier(0);           // pin: aA loads older than LOADB(t+3)
    if (t + 3 < NT) LOADB(t + 3, rfB);
    LGWB();
    COMPUTE(1, aB);                              // waits aB only
  }

  // ---- epilogue: bias, bf16 store
  #pragma unroll
  for (int mi = 0; mi < 4; ++mi) {
    #pragma unroll
    for (int r = 0; r < 4; ++r) {
      int o = wm * 64 + mi * 16 + lg * 4 + r;   // C/D: col=lane&15, row=(lane>>4)*4+reg
      float bo = bias[o];
      #pragma unroll
      for (int ni = 0; ni < 4; ++ni) {
        int pix = pix0 + wn * 64 + ni * 16 + lr;
        Cout[((size_t)(b * HID + o)) * HW + pix] = f2bf(acc[mi][ni][r] + bo);
      }
    }
  }
  __syncthreads();
  for (int e = tid; e < 1024; e += 512)
    atomicAdd(&ctx_sum[(size_t)b * 1024 + e], ctx_lds[e]);
}

// ============ GEMM2 fused with depthwise conv ============
// out_trans[b][o][pix] = sum_ch out_w[o][ch] * dw[b][ch][pix] + out_b[o]
// dw computed on the fly from xt (LDS slab). lgkm-only K-loop barriers; BN
// epilogue ni-pre-summed (R10 win).
__global__ __launch_bounds__(512, 2)
void gemm2_fused_kernel(const unsigned short* __restrict__ Afrag,
                        const unsigned short* __restrict__ xt,
                        const float* __restrict__ kern, const float* __restrict__ bias,
                        unsigned short* __restrict__ Cout, float* __restrict__ bn_sums)
{
  constexpr int NT = 4;                          // KDIM 256 / 64
  __shared__ unsigned short B_sh[128 * 64];      // [pix][k] bf16, XOR-swizzled
  __shared__ unsigned short xs[64 * 260];        // [ch][4 rows][64], stride 260 (bank-spread)
  __shared__ float kf_s[72];
  __shared__ float bn_lds[512];

  const int tid  = threadIdx.x;
  const int lane = tid & 63;
  const int wv   = tid >> 6;
  const int wm   = wv >> 1, wn = wv & 1;
  const int lr   = lane & 15, lg = lane >> 4;

  const int b    = blockIdx.x >> 5;
  const int R    = blockIdx.x & 31;              // pixel tile: image rows 2R, 2R+1
  const int pix0 = R << 7;
  const int g0   = R << 1;

  if (tid < 512) bn_lds[tid] = 0.f;
  if (tid < 72)  kf_s[tid] = kern[b * 72 + tid];
  __syncthreads();

  f32x4 acc[4][4] = {};
  const int c4 = tid & 15, q = tid >> 4;
  const int prow  = q >> 4;                      // 0|1 image row within tile
  const int pcol4 = (q & 15) << 2;               // col base 0..60
  const int grp9  = (c4 >> 3) * 9;               // kf sub-index (plus 2t*9 per tile)

  const char* abase = (const char*)Afrag + wm * 8192 + lane * 16;

  bf16x8 aA[8];
  us8 rx[4];

  auto PREXS = [&](int t) {
    #pragma unroll
    for (int it = 0; it < 4; ++it) {
      int flat = it * 512 + tid;
      int ch = flat >> 5, r4 = (flat >> 3) & 3, c8 = flat & 7;
      int grow = g0 - 1 + r4;
      if ((unsigned)grow < 64u) {
        rx[it] = *(const us8*)(xt + ((size_t)(b * HID + t * 64 + ch) << 12) + grow * 64 + c8 * 8);
      } else {
        us8 z = {0, 0, 0, 0, 0, 0, 0, 0}; rx[it] = z;
      }
    }
  };
  auto WRXS = [&]() {
    #pragma unroll
    for (int it = 0; it < 4; ++it) {
      int flat = it * 512 + tid;
      int ch = flat >> 5, r4 = (flat >> 3) & 3, c8 = flat & 7;
      int o = ch * 260 + r4 * 64 + c8 * 8;
      *(us4*)(xs + o)     = *(const us4*)(&rx[it].v[0]);
      *(us4*)(xs + o + 4) = *(const us4*)(&rx[it].v[4]);
    }
  };
  auto ISSUE_A = [&](int t) {
    const char* p = abase + t * 32768;
    #pragma unroll
    for (int i = 0; i < 8; ++i) aA[i] = *(const bf16x8*)(p + i * 1024);
  };

  PREXS(0);
  ISSUE_A(0);

  for (int t = 0; t < NT; ++t) {
    WRXS();                                      // waits PREXS(t) only (FIFO: aA younger)
    LGWB();                                      // xs visible; vmem stays in flight
    if (t + 1 < NT) PREXS(t + 1);                // flies under dw-compute + MFMA
    // ---- depthwise 3x3 from xs -> B_sh (swizzled)
    {
      const float k0 = kf_s[2 * t * 9 + grp9 + 0], k1 = kf_s[2 * t * 9 + grp9 + 1], k2 = kf_s[2 * t * 9 + grp9 + 2];
      const float k3 = kf_s[2 * t * 9 + grp9 + 3], k4 = kf_s[2 * t * 9 + grp9 + 4], k5 = kf_s[2 * t * 9 + grp9 + 5];
      const float k6 = kf_s[2 * t * 9 + grp9 + 6], k7 = kf_s[2 * t * 9 + grp9 + 7], k8 = kf_s[2 * t * 9 + grp9 + 8];
      float dwv[4][4];
      #pragma unroll
      for (int i = 0; i < 4; ++i) {
        int ch = 4 * c4 + i;
        #pragma unroll
        for (int j = 0; j < 4; ++j) dwv[i][j] = 0.f;
        #pragma unroll
        for (int ky = 0; ky < 3; ++ky) {
          int ro = ch * 260 + (prow + ky) * 64;
          float v[6];
          unsigned int p0 = (pcol4 > 0)  ? *(const unsigned int*)(xs + ro + pcol4 - 2) : 0u;
          unsigned int p1 = *(const unsigned int*)(xs + ro + pcol4);
          unsigned int p2 = *(const unsigned int*)(xs + ro + pcol4 + 2);
          unsigned int p3 = (pcol4 < 60) ? *(const unsigned int*)(xs + ro + pcol4 + 4) : 0u;
          v[0] = bf2f((unsigned short)(p0 >> 16));
          v[1] = bf2f((unsigned short)(p1 & 0xffff));
          v[2] = bf2f((unsigned short)(p1 >> 16));
          v[3] = bf2f((unsigned short)(p2 & 0xffff));
          v[4] = bf2f((unsigned short)(p2 >> 16));
          v[5] = bf2f((unsigned short)(p3 & 0xffff));
          float ka = (ky == 0) ? k0 : (ky == 1) ? k3 : k6;
          float kb = (ky == 0) ? k1 : (ky == 1) ? k4 : k7;
          float kc = (ky == 0) ? k2 : (ky == 1) ? k5 : k8;
          #pragma unroll
          for (int j = 0; j < 4; ++j)
            dwv[i][j] += v[j] * ka + v[j + 1] * kb + v[j + 2] * kc;
        }
      }
      #pragma unroll
      for (int j = 0; j < 4; ++j) {
        int pix = 4 * q + j;
        us4 w = { f2bf(dwv[0][j]), f2bf(dwv[1][j]), f2bf(dwv[2][j]), f2bf(dwv[3][j]) };
        *(us4*)((char*)B_sh + pix * 128 + ((8 * c4) ^ ((pix & 7) << 4))) = w;
      }
    }
    LGWB();                                      // B_sh visible; PREXS(t+1) stays in flight
    // ---- MFMA
    #pragma unroll
    for (int kk = 0; kk < 2; ++kk) {
      bf16x8 bfr[4];
      #pragma unroll
      for (int ni = 0; ni < 4; ++ni) {
        int pr = wn * 64 + ni * 16 + lr;
        bfr[ni] = *(const bf16x8*)((const char*)B_sh + pr * 128 + ((((kk << 2) | lg) ^ (pr & 7)) << 4));
      }
      #pragma unroll
      for (int mi = 0; mi < 4; ++mi)
        #pragma unroll
        for (int ni = 0; ni < 4; ++ni)
          acc[mi][ni] = __builtin_amdgcn_mfma_f32_16x16x32_bf16(aA[kk * 4 + mi], bfr[ni], acc[mi][ni], 0, 0, 0);
    }
    if (t + 1 < NT) ISSUE_A(t + 1);              // after MFMA: aA regs free (single buffer)
  }

  // ---- epilogue: bias, bf16 store, BN stats (ni pre-summed: 4x fewer shuffles)
  #pragma unroll
  for (int mi = 0; mi < 4; ++mi) {
    #pragma unroll
    for (int r = 0; r < 4; ++r) {
      int o = wm * 64 + mi * 16 + lg * 4 + r;
      float bo = bias[o];
      float s = 0.f, s2 = 0.f;
      #pragma unroll
      for (int ni = 0; ni < 4; ++ni) {
        int pix = pix0 + wn * 64 + ni * 16 + lr;
        float val = acc[mi][ni][r] + bo;
        Cout[((size_t)(b * HID + o)) * HW + pix] = f2bf(val);
        s += val; s2 += val * val;
      }
      #pragma unroll
      for (int msk = 1; msk < 16; msk <<= 1) {
        s  += __shfl_xor(s,  msk, 64);
        s2 += __shfl_xor(s2, msk, 64);
      }
      if (lr == 0) { atomicAdd(&bn_lds[o], s); atomicAdd(&bn_lds[256 + o], s2); }
    }
  }
  __syncthreads();
  if (tid < 512) atomicAdd(&bn_sums[tid], bn_lds[tid]);
}

// wave-per-output FC layer: out[b][o] = act(scale * dot(in[b][:], w[o][:]) + bias[o])
template<int K, int N, bool RELU>
__global__ __launch_bounds__(256)
void fc_kernel(const float* __restrict__ in, const float* __restrict__ w,
               const float* __restrict__ bias, float* __restrict__ out, float scale)
{
  const int wid  = (blockIdx.x << 2) | (threadIdx.x >> 6);
  const int lane = threadIdx.x & 63;
  const int b = wid / N, o = wid - b * N;
  const float* ip = in + (size_t)b * K;
  const float* wp = w  + (size_t)o * K;
  float p = 0.f;
  #pragma unroll
  for (int k = 0; k < K / 64; ++k) p += ip[lane + k * 64] * wp[lane + k * 64];
  #pragma unroll
  for (int m = 1; m < 64; m <<= 1) p += __shfl_xor(p, m, 64);
  if (lane == 0) {
    float v = p * scale + bias[o];
    out[(size_t)b * N + o] = RELU ? fmaxf(v, 0.f) : v;
  }
}

// out = xt + scale[o]*ot + shift[o]; BN finalize folded in (per-block from bn_sums)
__global__ __launch_bounds__(256)
void final_kernel(const unsigned short* __restrict__ xt, const unsigned short* __restrict__ ot,
                  const float* __restrict__ bn_sums, const float* __restrict__ gamma,
                  const float* __restrict__ beta, float* __restrict__ out)
{
  __shared__ float sc_s[256], sh_s[256];
  {
    int t = threadIdx.x;
    const float inv_n = 1.f / 65536.f;          // B*H*W
    float m  = bn_sums[t] * inv_n;
    float v  = bn_sums[256 + t] * inv_n - m * m;
    float sc = gamma[t] * rsqrtf(v + 1e-5f);
    sc_s[t] = sc;
    sh_s[t] = beta[t] - m * sc;
  }
  __syncthreads();
  int g = blockIdx.x * 256 + threadIdx.x;       // group of 4 elements
  const int stride = 4096 * 256;
  #pragma unroll
  for (int it = 0; it < 4; ++it, g += stride) {
    int o = (g >> 10) & 255;
    us4 a = ((const us4*)xt)[g];
    us4 c = ((const us4*)ot)[g];
    float s = sc_s[o], h = sh_s[o];
    f4 r;
    #pragma unroll
    for (int j = 0; j < 4; ++j) r.v[j] = bf2f(a.v[j]) + s * bf2f(c.v[j]) + h;
    *(f4*)(out + (size_t)g * 4) = r;
  }
}

extern "C" void kernel_launch(void* const* d_in, const int* in_sizes, int n_in,
                              void* d_out, int out_size, void* d_ws, size_t ws_size,
                              hipStream_t stream)
{
  const float* x     = (const float*)d_in[0];
  const float* ctx_w = (const float*)d_in[1];
  const float* ctx_b = (const float*)d_in[2];
  const float* kg_w1 = (const float*)d_in[3];
  const float* kg_b1 = (const float*)d_in[4];
  const float* kg_w2 = (const float*)d_in[5];
  const float* kg_b2 = (const float*)d_in[6];
  const float* in_w  = (const float*)d_in[7];
  const float* in_b  = (const float*)d_in[8];
  const float* out_w = (const float*)d_in[9];
  const float* out_b = (const float*)d_in[10];
  const float* gamma = (const float*)d_in[11];
  const float* beta  = (const float*)d_in[12];
  float* out = (float*)d_out;

  char* ws = (char*)d_ws;
  unsigned short* xt = (unsigned short*)ws;                  // 32 MiB bf16 xt
  unsigned short* ot = (unsigned short*)(ws + 33554432);     // 32 MiB bf16 out_trans
  float* ctx_sum = (float*)(ws + 67108864);                  // [16][1024]
  float* bn_sums = ctx_sum + 16384;                          // [512] (zeroed by prep)
  float* kern    = bn_sums + 512;                            // [16][72]
  float* ctxbuf  = kern + 1152;                              // [16][256]
  float* hddnbuf = ctxbuf + 4096;                            // [16][512]
  unsigned short* afrag1 = (unsigned short*)(ws + 67108864 + 131072);            // 512 KiB
  unsigned short* afrag2 = (unsigned short*)(ws + 67108864 + 131072 + 524288);   // 128 KiB

  prep_kernel<<<226, 256, 0, stream>>>(in_w, afrag1, out_w, afrag2, ctx_sum);
  gemm1_kernel<<<512, 512, 0, stream>>>(afrag1, x, in_b, xt, ctx_sum);
  fc_kernel<1024, 256, true ><<<1024, 256, 0, stream>>>(ctx_sum, ctx_w, ctx_b, ctxbuf, 1.f / 4096.f);
  fc_kernel< 256, 512, true ><<<2048, 256, 0, stream>>>(ctxbuf,  kg_w1, kg_b1, hddnbuf, 1.f);
  fc_kernel< 512,  72, false><<< 288, 256, 0, stream>>>(hddnbuf, kg_w2, kg_b2, kern,    1.f);
  gemm2_fused_kernel<<<512, 512, 0, stream>>>(afrag2, xt, kern, out_b, ot, bn_sums);
  final_kernel<<<4096, 256, 0, stream>>>(xt, ot, bn_sums, gamma, beta, out);
}

// Round 17
// 162.037 us; speedup vs baseline: 1.3624x; 1.0126x over previous
//
#include <hip/hip_runtime.h>

#define BATCH 16
#define CIN   1024
#define HID   256
#define HW    4096

typedef __attribute__((ext_vector_type(8))) short bf16x8;
typedef __attribute__((ext_vector_type(4))) float f32x4;

struct __align__(16) f4  { float v[4]; };
struct __align__(8)  us4 { unsigned short v[4]; };
struct __align__(16) us8 { unsigned short v[8]; };

__device__ __forceinline__ float bf2f(unsigned short u) {
  unsigned int x = ((unsigned int)u) << 16;
  return __builtin_bit_cast(float, x);
}
__device__ __forceinline__ unsigned short f2bf(float f) {
  unsigned int u = __builtin_bit_cast(unsigned int, f);
  u += 0x7fff + ((u >> 16) & 1);            // round-to-nearest-even
  return (unsigned short)(u >> 16);
}

// lgkm-only barrier: drain ds ops, leave ALL vmem prefetch in flight
#define LGWB() do { __builtin_amdgcn_sched_barrier(0); \
  asm volatile("s_waitcnt lgkmcnt(0)" ::: "memory"); \
  __builtin_amdgcn_s_barrier(); \
  __builtin_amdgcn_sched_barrier(0); } while (0)

// Pre-convert fp32 [256][KD] weights into per-lane bf16 MFMA A-fragments:
// unit u -> [tile][wm][kk][mi][lane], 16 B each. Trailing blocks zero ctx/bn sums.
__global__ __launch_bounds__(256)
void prep_kernel(const float* __restrict__ A1, unsigned short* __restrict__ O1,
                 const float* __restrict__ A2, unsigned short* __restrict__ O2,
                 float* __restrict__ zbuf)
{
  const int bidx = blockIdx.x;
  if (bidx >= 160) {                        // zero ctx_sum[16384] + bn_sums[512]
    int idx = (bidx - 160) * 256 + threadIdx.x;
    if (idx < 16896) zbuf[idx] = 0.f;
    return;
  }
  const float* A; unsigned short* O; int KD, u;
  if (bidx < 128) { A = A1; O = O1; KD = 1024; u = bidx * 256 + threadIdx.x; }
  else            { A = A2; O = O2; KD = 256;  u = (bidx - 128) * 256 + threadIdx.x; }
  const int t    = u >> 11;                 // K-tile (2048 units of 16 B per tile)
  const int r    = u & 2047;
  const int wm   = r >> 9, kk = (r >> 8) & 1, mi = (r >> 6) & 3, lane = r & 63;
  const int row  = wm * 64 + mi * 16 + (lane & 15);
  const int k    = t * 64 + kk * 32 + (lane >> 4) * 8;
  f4 v0 = *(const f4*)(A + (size_t)row * KD + k);
  f4 v1 = *(const f4*)(A + (size_t)row * KD + k + 4);
  us8 w = { f2bf(v0.v[0]), f2bf(v0.v[1]), f2bf(v0.v[2]), f2bf(v0.v[3]),
            f2bf(v1.v[0]), f2bf(v1.v[1]), f2bf(v1.v[2]), f2bf(v1.v[3]) };
  *(us8*)(O + (size_t)u * 8) = w;
}

// ============ GEMM1: xt[b][m][pix] = sum_k in_w[m][k]*x[b][k][pix] + bias[m] ====
// R12 configuration (measured 73.8 us standalone): contiguous staging, cvt_pk+shfl
// transpose, swizzled LDS, depth-2 B prefetch, FIFO discipline, rolled loop.
__global__ __launch_bounds__(512, 2)
void gemm1_kernel(const unsigned short* __restrict__ Afrag, const float* __restrict__ xb,
                  const float* __restrict__ bias, unsigned short* __restrict__ Cout,
                  float* __restrict__ ctx_sum)
{
  constexpr int NT = 16;
  __shared__ unsigned short B_sh[2][128 * 64];   // [pix] rows of 8 swizzled 16-B slots
  __shared__ float ctx_lds[1024];

  const int tid  = threadIdx.x;
  const int lane = tid & 63;
  const int wv   = tid >> 6;
  const int wm   = wv >> 1, wn = wv & 1;         // wave grid 4(M) x 2(N), tile 64x64
  const int lr   = lane & 15, lg = lane >> 4;
  const int hi   = lane >> 5, q = lane & 31;

  const int b    = blockIdx.x >> 5;
  const int pix0 = (blockIdx.x & 31) << 7;

  for (int i = tid; i < 1024; i += 512) ctx_lds[i] = 0.f;
  __syncthreads();

  f32x4 acc[4][4] = {};
  const size_t rowbase = ((size_t)b * CIN + 8 * wv + hi) * HW + pix0 + 4 * q;
  const char*  abase   = (const char*)Afrag + wm * 8192 + lane * 16;

  bf16x8 aA[8], aB[8];                           // A frag double-buffer (regs)
  f4 rfA[4], rfB[4];                             // B prefetch sets

  auto ISSUE_A = [&](int t, bf16x8* a) {
    const char* p = abase + t * 32768;
    #pragma unroll
    for (int i = 0; i < 8; ++i) a[i] = *(const bf16x8*)(p + i * 1024);
  };
  auto LOADB = [&](int t, f4* rf) {
    const float* p = xb + rowbase + (size_t)t * 64 * HW;
    #pragma unroll
    for (int i = 0; i < 4; ++i) rf[i] = *(const f4*)(p + (size_t)(2 * i) * HW);
  };
  auto WRITEB = [&](int sel, int t, f4* rf) {
    // fused context-pool partial sums (each x element staged once)
    #pragma unroll
    for (int i = 0; i < 4; ++i) {
      float s = rf[i].v[0] + rf[i].v[1] + rf[i].v[2] + rf[i].v[3];
      #pragma unroll
      for (int m = 1; m < 32; m <<= 1) s += __shfl_xor(s, m, 64);
      if (q == 0) atomicAdd(&ctx_lds[t * 64 + 8 * wv + 2 * i + hi], s);
    }
    unsigned int u[4][2];
    #pragma unroll
    for (int i = 0; i < 4; ++i) {
      asm("v_cvt_pk_bf16_f32 %0, %1, %2" : "=v"(u[i][0]) : "v"(rf[i].v[0]), "v"(rf[i].v[1]));
      asm("v_cvt_pk_bf16_f32 %0, %1, %2" : "=v"(u[i][1]) : "v"(rf[i].v[2]), "v"(rf[i].v[3]));
    }
    unsigned int w[4][2];
    #pragma unroll
    for (int i = 0; i < 4; ++i) {
      w[i][0] = __shfl_xor(u[i][0], 32, 64);
      w[i][1] = __shfl_xor(u[i][1], 32, 64);
    }
    // ch-ordered quad (offsets 0..3): hi=0 -> [u0,w0,u1,w1]; hi=1 -> [w2,u2,w3,u3]
    #pragma unroll
    for (int jj = 0; jj < 2; ++jj) {
      unsigned int A0 = hi ? w[2][jj] : u[0][jj];
      unsigned int A1 = hi ? u[2][jj] : w[0][jj];
      unsigned int A2 = hi ? w[3][jj] : u[1][jj];
      unsigned int A3 = hi ? u[3][jj] : w[1][jj];
      #pragma unroll
      for (int sub = 0; sub < 2; ++sub) {
        unsigned int lo, h2;
        if (sub == 0) { lo = (A0 & 0xffffu) | (A1 << 16);  h2 = (A2 & 0xffffu) | (A3 << 16); }
        else          { lo = (A0 >> 16) | (A1 & 0xffff0000u); h2 = (A2 >> 16) | (A3 & 0xffff0000u); }
        int p  = 4 * q + jj * 2 + sub;
        int fx = ((p >> 2) ^ p) & 7;
        int byte = p * 128 + (((wv ^ fx) & 7) << 4) + hi * 8;
        uint2 val; val.x = lo; val.y = h2;
        *(uint2*)((char*)B_sh[sel] + byte) = val;
      }
    }
  };
  auto COMPUTE = [&](int sel, bf16x8* a) {
    #pragma unroll
    for (int kk = 0; kk < 2; ++kk) {
      bf16x8 bfr[4];
      #pragma unroll
      for (int ni = 0; ni < 4; ++ni) {
        int pr = wn * 64 + ni * 16 + lr;
        int fx = ((pr >> 2) ^ pr) & 7;
        int byte = pr * 128 + ((((kk * 4 + lg) ^ fx) & 7) << 4);
        bfr[ni] = *(const bf16x8*)((const char*)B_sh[sel] + byte);
      }
      #pragma unroll
      for (int mi = 0; mi < 4; ++mi)
        #pragma unroll
        for (int ni = 0; ni < 4; ++ni)
          acc[mi][ni] = __builtin_amdgcn_mfma_f32_16x16x32_bf16(a[kk * 4 + mi], bfr[ni], acc[mi][ni], 0, 0, 0);
    }
  };

  // prologue: A(0) + B(0),B(1) in flight
  ISSUE_A(0, aA);
  LOADB(0, rfA);
  LOADB(1, rfB);

  #pragma unroll
  for (int t = 0; t < NT; t += 2) {
    // ---- half 1: tile t (B_sh[0], aA). A-issue BEFORE B-issue (FIFO discipline).
    WRITEB(0, t, rfA);
    ISSUE_A(t + 1, aB);
    __builtin_amdgcn_sched_barrier(0);           // pin: aB loads older than LOADB(t+2)
    if (t + 2 < NT) LOADB(t + 2, rfA);
    LGWB();
    COMPUTE(0, aA);                              // waits aA only; B prefetch stays in flight
    // ---- half 2: tile t+1 (B_sh[1], aB)
    WRITEB(1, t + 1, rfB);
    if (t + 2 < NT) ISSUE_A(t + 2, aA);
    __builtin_amdgcn_sched_barrier(0);           // pin: aA loads older than LOADB(t+3)
    if (t + 3 < NT) LOADB(t + 3, rfB);
    LGWB();
    COMPUTE(1, aB);                              // waits aB only
  }

  // ---- epilogue: bias, bf16 store
  #pragma unroll
  for (int mi = 0; mi < 4; ++mi) {
    #pragma unroll
    for (int r = 0; r < 4; ++r) {
      int o = wm * 64 + mi * 16 + lg * 4 + r;   // C/D: col=lane&15, row=(lane>>4)*4+reg
      float bo = bias[o];
      #pragma unroll
      for (int ni = 0; ni < 4; ++ni) {
        int pix = pix0 + wn * 64 + ni * 16 + lr;
        Cout[((size_t)(b * HID + o)) * HW + pix] = f2bf(acc[mi][ni][r] + bo);
      }
    }
  }
  __syncthreads();
  for (int e = tid; e < 1024; e += 512)
    atomicAdd(&ctx_sum[(size_t)b * 1024 + e], ctx_lds[e]);
}

// ============ GEMM2 fused with depthwise conv ============
// out_trans[b][o][pix] = sum_ch out_w[o][ch] * dw[b][ch][pix] + out_b[o]
// dw computed on the fly from xt (LDS slab). lgkm-only K-loop barriers; BN
// epilogue ni-pre-summed (R10 win).
__global__ __launch_bounds__(512, 2)
void gemm2_fused_kernel(const unsigned short* __restrict__ Afrag,
                        const unsigned short* __restrict__ xt,
                        const float* __restrict__ kern, const float* __restrict__ bias,
                        unsigned short* __restrict__ Cout, float* __restrict__ bn_sums)
{
  constexpr int NT = 4;                          // KDIM 256 / 64
  __shared__ unsigned short B_sh[128 * 64];      // [pix][k] bf16, XOR-swizzled
  __shared__ unsigned short xs[64 * 260];        // [ch][4 rows][64], stride 260 (bank-spread)
  __shared__ float kf_s[72];
  __shared__ float bn_lds[512];

  const int tid  = threadIdx.x;
  const int lane = tid & 63;
  const int wv   = tid >> 6;
  const int wm   = wv >> 1, wn = wv & 1;
  const int lr   = lane & 15, lg = lane >> 4;

  const int b    = blockIdx.x >> 5;
  const int R    = blockIdx.x & 31;              // pixel tile: image rows 2R, 2R+1
  const int pix0 = R << 7;
  const int g0   = R << 1;

  if (tid < 512) bn_lds[tid] = 0.f;
  if (tid < 72)  kf_s[tid] = kern[b * 72 + tid];
  __syncthreads();

  f32x4 acc[4][4] = {};
  const int c4 = tid & 15, q = tid >> 4;
  const int prow  = q >> 4;                      // 0|1 image row within tile
  const int pcol4 = (q & 15) << 2;               // col base 0..60
  const int grp9  = (c4 >> 3) * 9;               // kf sub-index (plus 2t*9 per tile)

  const char* abase = (const char*)Afrag + wm * 8192 + lane * 16;

  bf16x8 aA[8];
  us8 rx[4];

  auto PREXS = [&](int t) {
    #pragma unroll
    for (int it = 0; it < 4; ++it) {
      int flat = it * 512 + tid;
      int ch = flat >> 5, r4 = (flat >> 3) & 3, c8 = flat & 7;
      int grow = g0 - 1 + r4;
      if ((unsigned)grow < 64u) {
        rx[it] = *(const us8*)(xt + ((size_t)(b * HID + t * 64 + ch) << 12) + grow * 64 + c8 * 8);
      } else {
        us8 z = {0, 0, 0, 0, 0, 0, 0, 0}; rx[it] = z;
      }
    }
  };
  auto WRXS = [&]() {
    #pragma unroll
    for (int it = 0; it < 4; ++it) {
      int flat = it * 512 + tid;
      int ch = flat >> 5, r4 = (flat >> 3) & 3, c8 = flat & 7;
      int o = ch * 260 + r4 * 64 + c8 * 8;
      *(us4*)(xs + o)     = *(const us4*)(&rx[it].v[0]);
      *(us4*)(xs + o + 4) = *(const us4*)(&rx[it].v[4]);
    }
  };
  auto ISSUE_A = [&](int t) {
    const char* p = abase + t * 32768;
    #pragma unroll
    for (int i = 0; i < 8; ++i) aA[i] = *(const bf16x8*)(p + i * 1024);
  };

  PREXS(0);
  ISSUE_A(0);

  for (int t = 0; t < NT; ++t) {
    WRXS();                                      // waits PREXS(t) only (FIFO: aA younger)
    LGWB();                                      // xs visible; vmem stays in flight
    if (t + 1 < NT) PREXS(t + 1);                // flies under dw-compute + MFMA
    // ---- depthwise 3x3 from xs -> B_sh (swizzled)
    {
      const float k0 = kf_s[2 * t * 9 + grp9 + 0], k1 = kf_s[2 * t * 9 + grp9 + 1], k2 = kf_s[2 * t * 9 + grp9 + 2];
      const float k3 = kf_s[2 * t * 9 + grp9 + 3], k4 = kf_s[2 * t * 9 + grp9 + 4], k5 = kf_s[2 * t * 9 + grp9 + 5];
      const float k6 = kf_s[2 * t * 9 + grp9 + 6], k7 = kf_s[2 * t * 9 + grp9 + 7], k8 = kf_s[2 * t * 9 + grp9 + 8];
      float dwv[4][4];
      #pragma unroll
      for (int i = 0; i < 4; ++i) {
        int ch = 4 * c4 + i;
        #pragma unroll
        for (int j = 0; j < 4; ++j) dwv[i][j] = 0.f;
        #pragma unroll
        for (int ky = 0; ky < 3; ++ky) {
          int ro = ch * 260 + (prow + ky) * 64;
          float v[6];
          unsigned int p0 = (pcol4 > 0)  ? *(const unsigned int*)(xs + ro + pcol4 - 2) : 0u;
          unsigned int p1 = *(const unsigned int*)(xs + ro + pcol4);
          unsigned int p2 = *(const unsigned int*)(xs + ro + pcol4 + 2);
          unsigned int p3 = (pcol4 < 60) ? *(const unsigned int*)(xs + ro + pcol4 + 4) : 0u;
          v[0] = bf2f((unsigned short)(p0 >> 16));
          v[1] = bf2f((unsigned short)(p1 & 0xffff));
          v[2] = bf2f((unsigned short)(p1 >> 16));
          v[3] = bf2f((unsigned short)(p2 & 0xffff));
          v[4] = bf2f((unsigned short)(p2 >> 16));
          v[5] = bf2f((unsigned short)(p3 & 0xffff));
          float ka = (ky == 0) ? k0 : (ky == 1) ? k3 : k6;
          float kb = (ky == 0) ? k1 : (ky == 1) ? k4 : k7;
          float kc = (ky == 0) ? k2 : (ky == 1) ? k5 : k8;
          #pragma unroll
          for (int j = 0; j < 4; ++j)
            dwv[i][j] += v[j] * ka + v[j + 1] * kb + v[j + 2] * kc;
        }
      }
      #pragma unroll
      for (int j = 0; j < 4; ++j) {
        int pix = 4 * q + j;
        us4 w = { f2bf(dwv[0][j]), f2bf(dwv[1][j]), f2bf(dwv[2][j]), f2bf(dwv[3][j]) };
        *(us4*)((char*)B_sh + pix * 128 + ((8 * c4) ^ ((pix & 7) << 4))) = w;
      }
    }
    LGWB();                                      // B_sh visible; PREXS(t+1) stays in flight
    // ---- MFMA
    #pragma unroll
    for (int kk = 0; kk < 2; ++kk) {
      bf16x8 bfr[4];
      #pragma unroll
      for (int ni = 0; ni < 4; ++ni) {
        int pr = wn * 64 + ni * 16 + lr;
        bfr[ni] = *(const bf16x8*)((const char*)B_sh + pr * 128 + ((((kk << 2) | lg) ^ (pr & 7)) << 4));
      }
      #pragma unroll
      for (int mi = 0; mi < 4; ++mi)
        #pragma unroll
        for (int ni = 0; ni < 4; ++ni)
          acc[mi][ni] = __builtin_amdgcn_mfma_f32_16x16x32_bf16(aA[kk * 4 + mi], bfr[ni], acc[mi][ni], 0, 0, 0);
    }
    if (t + 1 < NT) ISSUE_A(t + 1);              // after MFMA: aA regs free (single buffer)
  }

  // ---- epilogue: bias, bf16 store, BN stats (ni pre-summed: 4x fewer shuffles)
  #pragma unroll
  for (int mi = 0; mi < 4; ++mi) {
    #pragma unroll
    for (int r = 0; r < 4; ++r) {
      int o = wm * 64 + mi * 16 + lg * 4 + r;
      float bo = bias[o];
      float s = 0.f, s2 = 0.f;
      #pragma unroll
      for (int ni = 0; ni < 4; ++ni) {
        int pix = pix0 + wn * 64 + ni * 16 + lr;
        float val = acc[mi][ni][r] + bo;
        Cout[((size_t)(b * HID + o)) * HW + pix] = f2bf(val);
        s += val; s2 += val * val;
      }
      #pragma unroll
      for (int msk = 1; msk < 16; msk <<= 1) {
        s  += __shfl_xor(s,  msk, 64);
        s2 += __shfl_xor(s2, msk, 64);
      }
      if (lr == 0) { atomicAdd(&bn_lds[o], s); atomicAdd(&bn_lds[256 + o], s2); }
    }
  }
  __syncthreads();
  if (tid < 512) atomicAdd(&bn_sums[tid], bn_lds[tid]);
}

// wave-per-output FC layer: out[b][o] = act(scale * dot(in[b][:], w[o][:]) + bias[o])
template<int K, int N, bool RELU>
__global__ __launch_bounds__(256)
void fc_kernel(const float* __restrict__ in, const float* __restrict__ w,
               const float* __restrict__ bias, float* __restrict__ out, float scale)
{
  const int wid  = (blockIdx.x << 2) | (threadIdx.x >> 6);
  const int lane = threadIdx.x & 63;
  const int b = wid / N, o = wid - b * N;
  const float* ip = in + (size_t)b * K;
  const float* wp = w  + (size_t)o * K;
  float p = 0.f;
  #pragma unroll
  for (int k = 0; k < K / 64; ++k) p += ip[lane + k * 64] * wp[lane + k * 64];
  #pragma unroll
  for (int m = 1; m < 64; m <<= 1) p += __shfl_xor(p, m, 64);
  if (lane == 0) {
    float v = p * scale + bias[o];
    out[(size_t)b * N + o] = RELU ? fmaxf(v, 0.f) : v;
  }
}

// out = xt + scale[o]*ot + shift[o]; BN finalize folded in. 16-B us8 loads (G13).
__global__ __launch_bounds__(256)
void final_kernel(const unsigned short* __restrict__ xt, const unsigned short* __restrict__ ot,
                  const float* __restrict__ bn_sums, const float* __restrict__ gamma,
                  const float* __restrict__ beta, float* __restrict__ out)
{
  __shared__ float sc_s[256], sh_s[256];
  {
    int t = threadIdx.x;
    const float inv_n = 1.f / 65536.f;          // B*H*W
    float m  = bn_sums[t] * inv_n;
    float v  = bn_sums[256 + t] * inv_n - m * m;
    float sc = gamma[t] * rsqrtf(v + 1e-5f);
    sc_s[t] = sc;
    sh_s[t] = beta[t] - m * sc;
  }
  __syncthreads();
  int g8 = blockIdx.x * 256 + threadIdx.x;      // 8-element group index
  const int stride8 = 4096 * 256;               // total 8-groups = 2 * stride8
  #pragma unroll
  for (int it = 0; it < 2; ++it, g8 += stride8) {
    int o = (g8 >> 9) & 255;                    // e = g8*8; o = (e>>12) & 255
    us8 a = ((const us8*)xt)[g8];
    us8 c = ((const us8*)ot)[g8];
    float s = sc_s[o], h = sh_s[o];
    f4 r0, r1;
    #pragma unroll
    for (int j = 0; j < 4; ++j) r0.v[j] = bf2f(a.v[j])     + s * bf2f(c.v[j])     + h;
    #pragma unroll
    for (int j = 0; j < 4; ++j) r1.v[j] = bf2f(a.v[4 + j]) + s * bf2f(c.v[4 + j]) + h;
    *(f4*)(out + (size_t)g8 * 8)     = r0;
    *(f4*)(out + (size_t)g8 * 8 + 4) = r1;
  }
}

extern "C" void kernel_launch(void* const* d_in, const int* in_sizes, int n_in,
                              void* d_out, int out_size, void* d_ws, size_t ws_size,
                              hipStream_t stream)
{
  const float* x     = (const float*)d_in[0];
  const float* ctx_w = (const float*)d_in[1];
  const float* ctx_b = (const float*)d_in[2];
  const float* kg_w1 = (const float*)d_in[3];
  const float* kg_b1 = (const float*)d_in[4];
  const float* kg_w2 = (const float*)d_in[5];
  const float* kg_b2 = (const float*)d_in[6];
  const float* in_w  = (const float*)d_in[7];
  const float* in_b  = (const float*)d_in[8];
  const float* out_w = (const float*)d_in[9];
  const float* out_b = (const float*)d_in[10];
  const float* gamma = (const float*)d_in[11];
  const float* beta  = (const float*)d_in[12];
  float* out = (float*)d_out;

  char* ws = (char*)d_ws;
  unsigned short* xt = (unsigned short*)ws;                  // 32 MiB bf16 xt
  unsigned short* ot = (unsigned short*)(ws + 33554432);     // 32 MiB bf16 out_trans
  float* ctx_sum = (float*)(ws + 67108864);                  // [16][1024]
  float* bn_sums = ctx_sum + 16384;                          // [512] (zeroed by prep)
  float* kern    = bn_sums + 512;                            // [16][72]
  float* ctxbuf  = kern + 1152;                              // [16][256]
  float* hddnbuf = ctxbuf + 4096;                            // [16][512]
  unsigned short* afrag1 = (unsigned short*)(ws + 67108864 + 131072);            // 512 KiB
  unsigned short* afrag2 = (unsigned short*)(ws + 67108864 + 131072 + 524288);   // 128 KiB

  prep_kernel<<<226, 256, 0, stream>>>(in_w, afrag1, out_w, afrag2, ctx_sum);
  gemm1_kernel<<<512, 512, 0, stream>>>(afrag1, x, in_b, xt, ctx_sum);
  fc_kernel<1024, 256, true ><<<1024, 256, 0, stream>>>(ctx_sum, ctx_w, ctx_b, ctxbuf, 1.f / 4096.f);
  fc_kernel< 256, 512, true ><<<2048, 256, 0, stream>>>(ctxbuf,  kg_w1, kg_b1, hddnbuf, 1.f);
  fc_kernel< 512,  72, false><<< 288, 256, 0, stream>>>(hddnbuf, kg_w2, kg_b2, kern,    1.f);
  gemm2_fused_kernel<<<512, 512, 0, stream>>>(afrag2, xt, kern, out_b, ot, bn_sums);
  final_kernel<<<4096, 256, 0, stream>>>(xt, ot, bn_sums, gamma, beta, out);
}